// Round 1
// baseline (928.108 us; speedup 1.0000x reference)
//
#include <hip/hip_runtime.h>
#include <cstdint>

#define NROW 192
#define NW   262144
#define NT   1024
#define QCAP 1024
#define SEGS_CAP 8192

// ---------- monotone float<->uint transform (total order) ----------
__device__ __forceinline__ uint32_t mono(float x) {
    uint32_t u = __float_as_uint(x);
    return (u & 0x80000000u) ? ~u : (u | 0x80000000u);
}
__device__ __forceinline__ float unmono(uint32_t u) {
    uint32_t v = (u & 0x80000000u) ? (u & 0x7FFFFFFFu) : ~u;
    return __uint_as_float(v);
}
// linear-in-value bin; MUST be the same code in hist and collect sweeps
__device__ __forceinline__ int binof(float x, float lo, float s) {
    float d = (x - lo) * s;
    d = fminf(fmaxf(d, 0.0f), 4095.0f);
    return (int)d;
}

// ---------- block "find bin containing rank" (used by fallback path) ----------
__device__ void block_select(const uint32_t* hist, int nb, uint32_t rank,
                             uint32_t* sbuf, volatile uint32_t* out, int tid) {
    int per = (nb + NT - 1) / NT;
    int base = tid * per;
    uint32_t s = 0;
    for (int i = 0; i < per; ++i) { int idx = base + i; if (idx < nb) s += hist[idx]; }
    uint32_t p = s;
    int lane = tid & 63;
    #pragma unroll
    for (int off = 1; off < 64; off <<= 1) {
        uint32_t v = __shfl_up(p, off);
        if (lane >= off) p += v;
    }
    int w = tid >> 6;
    if (lane == 63) sbuf[w] = p;
    __syncthreads();
    if (tid == 0) {
        uint32_t acc = 0;
        for (int i = 0; i < 16; ++i) { uint32_t t = sbuf[i]; sbuf[16 + i] = acc; acc += t; }
    }
    __syncthreads();
    uint32_t excl = sbuf[16 + w] + p - s;
    if (rank >= excl && rank < excl + s) {
        uint32_t rem = rank - excl;
        for (int i = 0; i < per; ++i) {
            int idx = base + i;
            if (idx >= nb) break;
            uint32_t c = hist[idx];
            if (rem < c) { out[0] = (uint32_t)idx; out[1] = rem; break; }
            rem -= c;
        }
    }
    __syncthreads();
}

// ---------- fallback: finish a rank with 2 global sweeps (12-bit mono, proven) ----------
__device__ uint32_t refine_global(const float4* p4, float med, int mode,
                                  uint32_t b1, uint32_t rem,
                                  uint32_t* hist2, uint32_t* sbuf,
                                  volatile uint32_t* out2, int tid) {
    for (int i = tid; i < 2048; i += NT) hist2[i] = 0;
    __syncthreads();
    for (int it = 0; it < 64; ++it) {
        float4 v = p4[tid + it * NT];
        float xs[4] = {v.x, v.y, v.z, v.w};
        #pragma unroll
        for (int c = 0; c < 4; ++c) {
            uint32_t u = mode ? __float_as_uint(fabsf(xs[c] - med)) : mono(xs[c]);
            if ((u >> 20) == b1) atomicAdd(&hist2[(u >> 9) & 2047u], 1u);
        }
    }
    __syncthreads();
    block_select(hist2, 2048, rem, sbuf, out2, tid);
    uint32_t b2 = out2[0], r2 = out2[1];
    __syncthreads();
    for (int i = tid; i < 512; i += NT) hist2[i] = 0;
    __syncthreads();
    for (int it = 0; it < 64; ++it) {
        float4 v = p4[tid + it * NT];
        float xs[4] = {v.x, v.y, v.z, v.w};
        #pragma unroll
        for (int c = 0; c < 4; ++c) {
            uint32_t u = mode ? __float_as_uint(fabsf(xs[c] - med)) : mono(xs[c]);
            if ((u >> 20) == b1 && ((u >> 9) & 2047u) == b2)
                atomicAdd(&hist2[u & 511u], 1u);
        }
    }
    __syncthreads();
    block_select(hist2, 512, r2, sbuf, out2, tid);
    uint32_t b3 = out2[0];
    __syncthreads();
    return (b1 << 20) + (b2 << 9) + b3;
}

// ---------- fallback path: full 12-bit 3-level select (slow, always correct) ----------
__device__ void fb_path(const float4* p4, float* feat, int row,
                        uint32_t* hist, uint32_t* hist2, uint32_t* sbuf,
                        volatile uint32_t* out2, int tid) {
    const uint32_t RANK6[6] = {65535u, 65536u, 131071u, 131072u, 196607u, 196608u};
    for (int i = tid; i < 4096; i += NT) hist[i] = 0;
    __syncthreads();
    for (int it = 0; it < 64; ++it) {
        float4 v = p4[tid + it * NT];
        float xs[4] = {v.x, v.y, v.z, v.w};
        #pragma unroll
        for (int c = 0; c < 4; ++c) atomicAdd(&hist[mono(xs[c]) >> 20], 1u);
    }
    __syncthreads();
    uint32_t bins[6], rems[6];
    for (int k = 0; k < 6; ++k) {
        block_select(hist, 4096, RANK6[k], sbuf, out2, tid);
        bins[k] = out2[0]; rems[k] = out2[1];
        __syncthreads();
    }
    float svv[6];
    for (int k = 0; k < 6; ++k)
        svv[k] = unmono(refine_global(p4, 0.f, 0, bins[k], rems[k], hist2, sbuf, out2, tid));
    if (tid == 0) {
        float* f = feat + row * 16;
        f[0] = svv[2];
        f[3] = 0.25f * svv[0] + 0.75f * svv[1];
        f[4] = 0.5f  * (svv[2] + svv[3]);
        f[5] = 0.75f * svv[4] + 0.25f * svv[5];
    }
    float med = svv[2];
    __syncthreads();
    for (int i = tid; i < 4096; i += NT) hist[i] = 0;
    __syncthreads();
    for (int it = 0; it < 64; ++it) {
        float4 v = p4[tid + it * NT];
        float xs[4] = {v.x, v.y, v.z, v.w};
        #pragma unroll
        for (int c = 0; c < 4; ++c)
            atomicAdd(&hist[__float_as_uint(fabsf(xs[c] - med)) >> 20], 1u);
    }
    __syncthreads();
    block_select(hist, 4096, 131071u, sbuf, out2, tid);
    uint32_t mb = out2[0], mr = out2[1];
    __syncthreads();
    uint32_t mu = refine_global(p4, med, 1, mb, mr, hist2, sbuf, out2, tid);
    if (tid == 0) feat[row * 16 + 1] = __uint_as_float(mu);
}

// ---------- prefix-sum helpers (hist holds exclusive prefix P after scan) ----------
__device__ __forceinline__ uint32_t Pv(const uint32_t* P, int k) {
    return (k >= 4096) ? (uint32_t)NW : P[k];
}
// upper bound on count(|x-med|<=tau) for any med in [mL,mR]
__device__ __forceinline__ uint32_t wup(float mL, float mR, float tau,
                                        float blo, float bsc, const uint32_t* P) {
    const int bR = binof(mR + tau, blo, bsc);
    const int bL = binof(mL - tau, blo, bsc);
    return Pv(P, bR + 1) - P[bL];
}
// lower bound on count(|x-med|<=tau) for any med in [mL,mR]
__device__ __forceinline__ uint32_t wlow(float mL, float mR, float tau,
                                         float blo, float bsc, const uint32_t* P) {
    const int bR = binof(mL + tau, blo, bsc);
    const int bL = binof(mR - tau, blo, bsc);
    const uint32_t a = P[bR];
    const uint32_t b = Pv(P, bL + 1);
    return (a > b) ? (a - b) : 0u;
}

// ---------- in-LDS bitonic sort of 512 floats; 256-thread group, block-wide barriers ----------
__device__ void bitonic512g(float* a, int t2) {
    for (int k = 2; k <= 512; k <<= 1) {
        for (int j = k >> 1; j > 0; j >>= 1) {
            __syncthreads();
            for (int i = t2; i < 512; i += 256) {
                int ixj = i ^ j;
                if (ixj > i) {
                    float x = a[i], y = a[ixj];
                    bool up = ((i & k) == 0);
                    if ((x > y) == up) { a[i] = y; a[ixj] = x; }
                }
            }
        }
    }
    __syncthreads();
}

// ---------- fused stats: blocks [0,NROW) = w-row robust stats (2 full sweeps),
// ----------              blocks [NROW, NROW+48) = b-row sorts (4 rows/block) ----------
__global__ __launch_bounds__(NT) void stats_kernel(const float* __restrict__ wsrc,
                                                   const float* __restrict__ bsrc,
                                                   float* __restrict__ feat) {
    const int tid = threadIdx.x;
    __shared__ uint32_t hist[4096];      // counts, then in-place exclusive prefix P
    __shared__ uint32_t sbuf[1024];      // scan partials / byte table / reductions
    __shared__ uint32_t segs[SEGS_CAP];  // quantile segs (exact-packed) + MAD window; fb aliases hist2 here
    __shared__ uint32_t ctrl[64];
    __shared__ float fctrl[8];

    // ================= b-row branch: 4 rows per block, groups of 256 =================
    if (blockIdx.x >= NROW) {
        const int g = tid >> 8, t2 = tid & 255;
        const int brow = (blockIdx.x - NROW) * 4 + g;
        float* a = ((float*)segs) + g * 512;
        float* d = ((float*)segs) + 2048 + g * 512;
        const float* p = bsrc + (size_t)brow * 512;
        for (int i = t2; i < 512; i += 256) a[i] = p[i];
        bitonic512g(a, t2);
        const float bmed = a[255];
        if (t2 == 0) {
            float* f = feat + brow * 16;
            f[7]  = bmed;
            f[9]  = a[0];
            f[10] = 0.25f * a[127] + 0.75f * a[128];
            f[11] = 0.5f  * (a[255] + a[256]);
            f[12] = 0.75f * a[383] + 0.25f * a[384];
            f[13] = a[511];
        }
        __syncthreads();
        for (int i = t2; i < 512; i += 256) d[i] = fabsf(a[i] - bmed);
        bitonic512g(d, t2);
        if (t2 == 0) feat[brow * 16 + 8] = d[255];
        return;
    }

    // ================= w-row branch =================
    const int row = blockIdx.x;
    const float4* __restrict__ p4 = (const float4*)(wsrc + (size_t)row * NW);
    const int lane = tid & 63, wv = tid >> 6;
    float* fsb = (float*)sbuf;
    volatile uint32_t* out2 = (volatile uint32_t*)(ctrl + 62);

    // ---- P0: contiguous prefix sample (32768 floats) -> linear-bin range ----
    {
        float smin = 1e30f, smax = -1e30f;
        #pragma unroll
        for (int k = 0; k < 8; ++k) {
            float4 v = p4[tid + k * NT];
            smin = fminf(smin, fminf(fminf(v.x, v.y), fminf(v.z, v.w)));
            smax = fmaxf(smax, fmaxf(fmaxf(v.x, v.y), fmaxf(v.z, v.w)));
        }
        #pragma unroll
        for (int off = 32; off > 0; off >>= 1) {
            smin = fminf(smin, __shfl_down(smin, off));
            smax = fmaxf(smax, __shfl_down(smax, off));
        }
        if (lane == 0) { fsb[wv * 2] = smin; fsb[wv * 2 + 1] = smax; }
        __syncthreads();
        if (tid == 0) {
            float mn = 1e30f, mx = -1e30f;
            for (int i = 0; i < 16; ++i) { mn = fminf(mn, fsb[i * 2]); mx = fmaxf(mx, fsb[i * 2 + 1]); }
            float span = mx - mn;
            float lo = mn - 0.0625f * span;
            float s = (span > 0.f) ? 4096.0f / (span * 1.125f) : 0.0f;
            fctrl[0] = lo; fctrl[1] = s;
        }
        __syncthreads();
    }
    const float blo = fctrl[0], bsc = fctrl[1];

    // ---- S1: full sweep — linear hist + sum + exact min/max ----
    for (int i = tid; i < 4096; i += NT) hist[i] = 0;
    __syncthreads();
    {
        float sum = 0.f, fmn = 1e30f, fmx = -1e30f;
        for (int it = 0; it < 64; it += 8) {
            float4 a8[8];
            #pragma unroll
            for (int j = 0; j < 8; ++j) a8[j] = p4[tid + (it + j) * NT];
            #pragma unroll
            for (int j = 0; j < 8; ++j) {
                float xs[4] = {a8[j].x, a8[j].y, a8[j].z, a8[j].w};
                #pragma unroll
                for (int c = 0; c < 4; ++c) {
                    float x = xs[c];
                    sum += x;
                    fmn = fminf(fmn, x);
                    fmx = fmaxf(fmx, x);
                    atomicAdd(&hist[binof(x, blo, bsc)], 1u);
                }
            }
        }
        #pragma unroll
        for (int off = 32; off > 0; off >>= 1) {
            sum += __shfl_down(sum, off);
            fmn = fminf(fmn, __shfl_down(fmn, off));
            fmx = fmaxf(fmx, __shfl_down(fmx, off));
        }
        __syncthreads();
        if (lane == 0) { fsb[wv * 4] = sum; fsb[wv * 4 + 1] = fmn; fsb[wv * 4 + 2] = fmx; }
        __syncthreads();
        if (tid == 0) { float s = 0; for (int i = 0; i < 16; ++i) s += fsb[i * 4]; feat[row * 16 + 14] = s * (1.0f / (float)NW); }
        if (tid == 1) { float m = 1e30f;  for (int i = 0; i < 16; ++i) m = fminf(m, fsb[i * 4 + 1]); feat[row * 16 + 2] = m; fctrl[2] = m; }
        if (tid == 2) { float M = -1e30f; for (int i = 0; i < 16; ++i) M = fmaxf(M, fsb[i * 4 + 2]); feat[row * 16 + 6] = M; fctrl[3] = M; }
        if (tid == 3) feat[row * 16 + 15] = 0.0f;
        __syncthreads();
    }

    // ---- SCAN: in-place hist -> exclusive prefix P; fused rank->bin find ----
    {
        const int b4 = tid * 4;
        const uint32_t v0 = hist[b4], v1 = hist[b4 + 1], v2 = hist[b4 + 2], v3 = hist[b4 + 3];
        const uint32_t s = v0 + v1 + v2 + v3;
        uint32_t p = s;
        #pragma unroll
        for (int off = 1; off < 64; off <<= 1) {
            uint32_t t = __shfl_up(p, off);
            if (lane >= off) p += t;
        }
        if (lane == 63) sbuf[wv] = p;
        __syncthreads();
        if (tid == 0) {
            uint32_t acc = 0;
            for (int i = 0; i < 16; ++i) { uint32_t t = sbuf[i]; sbuf[16 + i] = acc; acc += t; }
        }
        __syncthreads();
        const uint32_t excl = sbuf[16 + wv] + p - s;
        uint32_t ppA[5];
        ppA[0] = excl; ppA[1] = excl + v0; ppA[2] = ppA[1] + v1; ppA[3] = ppA[2] + v2; ppA[4] = ppA[3] + v3;
        hist[b4] = ppA[0]; hist[b4 + 1] = ppA[1]; hist[b4 + 2] = ppA[2]; hist[b4 + 3] = ppA[3];
        const uint32_t RANKS[6] = {65535u, 65536u, 131071u, 131072u, 196607u, 196608u};
        #pragma unroll
        for (int c = 0; c < 4; ++c) {
            #pragma unroll
            for (int q = 0; q < 6; ++q) {
                const uint32_t r = RANKS[q];
                if (ppA[c] <= r && r < ppA[c + 1]) {
                    ctrl[12 + q] = (uint32_t)(b4 + c);   // bin
                    ctrl[18 + q] = r - ppA[c];           // rem within bin
                    ctrl[48 + q] = ppA[c + 1] - ppA[c];  // bin count
                }
            }
        }
        __syncthreads();
    }

    // ---- dedup rank bins; exact-packed seg bases; init cursors/flags ----
    if (tid == 0) {
        uint32_t ndl = 0, fail = 0;
        #pragma unroll
        for (int q = 0; q < 6; ++q) {
            const uint32_t b = ctrl[12 + q];
            int jf = -1;
            for (uint32_t t = 0; t < ndl; ++t) if (ctrl[24 + t] == b) { jf = (int)t; break; }
            if (jf < 0) {
                jf = (int)ndl;
                ctrl[24 + ndl] = b;
                ctrl[30 + ndl] = ctrl[48 + q];
                ndl++;
            }
            ctrl[36 + q] = (uint32_t)jf;
        }
        uint32_t off = 0;
        for (uint32_t t = 0; t < ndl; ++t) {
            ctrl[54 + t] = off;
            if (ctrl[30 + t] > QCAP) fail = 1;
            off += ctrl[30 + t];
        }
        if (off > 6144u) fail = 1;                       // keep >=2048 MAD slots
        if (ctrl[14] == 0u || ctrl[14] == 4095u) fail = 1; // med in clamped bin: bin-center bound invalid
        ctrl[60] = off;   // MAD region base
        ctrl[10] = ndl;
        ctrl[11] = fail;
        #pragma unroll
        for (int j = 0; j < 6; ++j) ctrl[j] = 0;         // quantile cursors
        ctrl[6] = 0;  // MAD cursor
        ctrl[7] = 0;  // c_lo
        ctrl[8] = 0;  // n2theta
        ctrl[9] = 0;  // n2c
        ctrl[48] = 0xFFFFFFFFu; ctrl[49] = 0xFFFFFFFFu;  // window jlo/jhi
    }
    __syncthreads();
    if (ctrl[11]) { fb_path(p4, feat, row, hist, segs, sbuf, out2, tid); return; }

    const float wbin = 1.0f / bsc;
    const uint32_t m0 = ctrl[14];

    // ---- zero candidate-bin byte table + MAD window bounds from P (parallel) ----
    sbuf[tid] = 0;
    {
        const float mLf = blo + (float)m0 * wbin;
        const float mRf = mLf + wbin;
        #pragma unroll
        for (int c = 0; c < 4; ++c) {
            const int j = tid * 4 + c;
            const float tau = (float)j * wbin;
            const uint32_t up_j = wup(mLf, mRf, tau, blo, bsc, hist);
            if (up_j <= 131071u) {   // largest j with up<=K  (up monotone in j)
                bool bnd = (j == 4095);
                if (!bnd) bnd = (wup(mLf, mRf, (float)(j + 1) * wbin, blo, bsc, hist) > 131071u);
                if (bnd) ctrl[48] = (uint32_t)j;
            }
            const uint32_t lo_j = wlow(mLf, mRf, tau, blo, bsc, hist);
            if (lo_j >= 131072u) {   // smallest j with low>=K+1 (low monotone in j)
                bool bnd = (j == 0);
                if (!bnd) bnd = (wlow(mLf, mRf, (float)(j - 1) * wbin, blo, bsc, hist) < 131072u);
                if (bnd) ctrl[49] = (uint32_t)j;
            }
        }
    }
    __syncthreads();
    if (tid < (int)ctrl[10]) ((uint8_t*)sbuf)[ctrl[24 + tid]] = (uint8_t)(tid + 1);
    const uint32_t jlo = ctrl[48], jhi = ctrl[49];
    float Awin = (jlo == 0xFFFFFFFFu) ? -1.0f : (float)jlo * wbin;
    float Bwin = (jhi == 0xFFFFFFFFu) ? 3.0e38f : (float)jhi * wbin;
    Bwin = fmaxf(Bwin, Awin + 3.0f * wbin);              // required margin for check validity
    const float mtld = blo + ((float)m0 + 0.5f) * wbin;  // |med - mtld| <= w/2
    const uint32_t madbase = ctrl[60];
    __syncthreads();

    // ---- S2: single combined sweep — quantile candidates + MAD window + c_lo ----
    uint32_t myclo = 0;
    {
        const uint8_t* tbl = (const uint8_t*)sbuf;
        for (int it = 0; it < 64; it += 8) {
            float4 a8[8];
            #pragma unroll
            for (int j = 0; j < 8; ++j) a8[j] = p4[tid + (it + j) * NT];
            #pragma unroll
            for (int j = 0; j < 8; ++j) {
                float xs[4] = {a8[j].x, a8[j].y, a8[j].z, a8[j].w};
                #pragma unroll
                for (int c = 0; c < 4; ++c) {
                    float x = xs[c];
                    uint32_t m = tbl[binof(x, blo, bsc)];
                    if (m) {
                        uint32_t jj = m - 1u;
                        uint32_t pos = atomicAdd(&ctrl[jj], 1u);
                        if (pos < ctrl[30 + jj]) segs[ctrl[54 + jj] + pos] = mono(x);
                    }
                    float u = fabsf(x - mtld);
                    if (u <= Awin) myclo++;
                    else if (u <= Bwin) {
                        uint32_t pos = atomicAdd(&ctrl[6], 1u);
                        uint32_t slot = madbase + pos;
                        if (slot < SEGS_CAP) segs[slot] = __float_as_uint(x);
                    }
                }
            }
        }
    }
    __syncthreads();
    #pragma unroll
    for (int off = 32; off > 0; off >>= 1) myclo += __shfl_down(myclo, off);
    if (lane == 0) sbuf[wv] = myclo;
    __syncthreads();
    if (tid == 0) {
        uint32_t clo = 0;
        for (int i = 0; i < 16; ++i) clo += sbuf[i];
        ctrl[7] = clo;
        uint32_t fail = 0;
        const uint32_t ndl = ctrl[10];
        for (uint32_t j = 0; j < ndl; ++j) if (ctrl[j] != ctrl[30 + j]) fail = 1;
        if (ctrl[6] > SEGS_CAP - madbase) fail = 1;
        ctrl[11] = fail;
    }
    __syncthreads();
    if (ctrl[11]) { fb_path(p4, feat, row, hist, segs, sbuf, out2, tid); return; }

    // ---- all-pairs rank select: all 6 quantile ranks, one pass per dedup segment ----
    {
        const uint32_t ndl = ctrl[10];
        for (uint32_t j = 0; j < ndl; ++j) {
            const uint32_t cnt = ctrl[j];
            const uint32_t base = ctrl[54 + j];
            if ((uint32_t)tid < cnt) {
                const uint32_t key = segs[base + tid];
                uint32_t r = 0;
                for (uint32_t i = 0; i < cnt; ++i) {
                    const uint32_t ki = segs[base + i];
                    r += (ki < key || (ki == key && i < (uint32_t)tid)) ? 1u : 0u;
                }
                #pragma unroll
                for (int q = 0; q < 6; ++q)
                    if (ctrl[36 + q] == j && ctrl[18 + q] == r) ctrl[42 + q] = key;
            }
        }
    }
    __syncthreads();
    const float med = unmono(ctrl[44]);
    if (tid == 0) {
        float* f = feat + row * 16;
        f[0] = med;
        f[3] = 0.25f * unmono(ctrl[42]) + 0.75f * unmono(ctrl[43]);
        f[4] = 0.5f  * (med + unmono(ctrl[45]));
        f[5] = 0.75f * unmono(ctrl[46]) + 0.25f * unmono(ctrl[47]);
    }

    // ---- MAD: convert window x -> t = |x-med|, verify containment, all-pairs select ----
    const uint32_t mcnt = ctrl[6];
    const float thq = Awin + wbin;          // theta: all c_lo-counted elements have t < theta
    const float tcq = Bwin - 2.0f * wbin;   // tau_c: all non-window elements have t > tau_c
    float tk[8];
    uint32_t rr[8];
    uint32_t n2t = 0, n2c = 0;
    #pragma unroll
    for (int q = 0; q < 8; ++q) {
        const uint32_t i = (uint32_t)tid + (uint32_t)q * NT;
        float t = 3.0e38f;
        if (i < mcnt) {
            float x = __uint_as_float(segs[madbase + i]);
            t = fabsf(x - med);
            segs[madbase + i] = __float_as_uint(t);
            n2t += (t <= thq) ? 1u : 0u;
            n2c += (t <= tcq) ? 1u : 0u;
        }
        tk[q] = t;
        rr[q] = 0;
    }
    #pragma unroll
    for (int off = 32; off > 0; off >>= 1) {
        n2t += __shfl_down(n2t, off);
        n2c += __shfl_down(n2c, off);
    }
    if (lane == 0) { atomicAdd(&ctrl[8], n2t); atomicAdd(&ctrl[9], n2c); }
    __syncthreads();
    if (tid == 0) {
        const uint32_t clo = ctrl[7];
        uint32_t fail = 0;
        if (clo > 131071u) fail = 1;                    // MAD must be above counted set
        if (clo + ctrl[8] > 131071u) fail = 1;          // count(t<=theta) <= 131071 => MAD > theta
        if (clo + ctrl[9] < 131072u) fail = 1;          // count(t<=tau_c) >= 131072 => MAD <= tau_c
        if (!fail && (131071u - clo) >= mcnt) fail = 1; // target rank inside window
        ctrl[11] = fail;
    }
    __syncthreads();
    if (ctrl[11]) { fb_path(p4, feat, row, hist, segs, sbuf, out2, tid); return; }
    const uint32_t kR = 131071u - ctrl[7];
    if ((uint32_t)tid < mcnt) {
        for (uint32_t jj = 0; jj < mcnt; ++jj) {
            const float tj = __uint_as_float(segs[madbase + jj]);
            #pragma unroll
            for (int q = 0; q < 8; ++q) {
                const uint32_t idx = (uint32_t)tid + (uint32_t)q * NT;
                rr[q] += (tj < tk[q] || (tj == tk[q] && jj < idx)) ? 1u : 0u;
            }
        }
        #pragma unroll
        for (int q = 0; q < 8; ++q) {
            const uint32_t idx = (uint32_t)tid + (uint32_t)q * NT;
            if (idx < mcnt && rr[q] == kR) feat[row * 16 + 1] = tk[q];
        }
    }
}

// ---------- MLP head: one block per (l,b) row; reads the completed 16-feature vector ----------
__global__ __launch_bounds__(256) void mlp_kernel(
    const float* __restrict__ feat,
    const float* __restrict__ fc1_w, const float* __restrict__ fc1_b,
    const float* __restrict__ ln_w,  const float* __restrict__ ln_b,
    const float* __restrict__ gate_w, const float* __restrict__ gate_b,
    const float* __restrict__ fco_w,  const float* __restrict__ fco_b,
    const float* __restrict__ scale,  float* __restrict__ out) {
    const int row = blockIdx.x;
    const int tid = threadIdx.x;
    const int l = row >> 6;
    __shared__ float x[16], h[64], hg[64], stats[2];

    if (tid < 16) x[tid] = feat[row * 16 + tid];
    __syncthreads();

    if (tid == 0) {
        float mu = 0.f;
        for (int i = 0; i < 16; ++i) mu += x[i];
        mu *= (1.f / 16.f);
        float var = 0.f;
        for (int i = 0; i < 16; ++i) { float dd = x[i] - mu; var += dd * dd; }
        var *= (1.f / 16.f);
        stats[0] = mu; stats[1] = rsqrtf(var + 1e-5f);
    }
    __syncthreads();
    if (tid < 16) x[tid] = (x[tid] - stats[0]) * stats[1];
    __syncthreads();
    if (tid < 64) {
        const float* wv = fc1_w + ((size_t)l * 64 + tid) * 16;
        float acc = fc1_b[l * 64 + tid];
        #pragma unroll
        for (int i = 0; i < 16; ++i) acc += x[i] * wv[i];
        h[tid] = acc;
    }
    __syncthreads();
    if (tid == 0) {
        float mu = 0.f;
        for (int i = 0; i < 64; ++i) mu += h[i];
        mu *= (1.f / 64.f);
        float var = 0.f;
        for (int i = 0; i < 64; ++i) { float dd = h[i] - mu; var += dd * dd; }
        var *= (1.f / 64.f);
        stats[0] = mu; stats[1] = rsqrtf(var + 1e-5f);
    }
    __syncthreads();
    if (tid < 64) {
        float v = (h[tid] - stats[0]) * stats[1] * ln_w[l * 64 + tid] + ln_b[l * 64 + tid];
        h[tid] = 0.5f * v * (1.0f + erff(v * 0.70710678118654752f));
    }
    __syncthreads();
    if (tid < 64) {
        const float* wv = gate_w + ((size_t)l * 64 + tid) * 64;
        float acc = gate_b[l * 64 + tid];
        #pragma unroll
        for (int i = 0; i < 64; ++i) acc += h[i] * wv[i];
        float g = 1.0f / (1.0f + expf(-acc));
        hg[tid] = h[tid] * g;
    }
    __syncthreads();
    const float sc = scale[l];
    for (int o = tid; o < 512; o += 256) {
        const float* wv = fco_w + ((size_t)l * 512 + o) * 64;
        float acc = fco_b[l * 512 + o];
        #pragma unroll
        for (int i = 0; i < 64; ++i) acc += hg[i] * wv[i];
        out[(size_t)row * 512 + o] = sinf(acc) * sc + 1.0f;
    }
}

extern "C" void kernel_launch(void* const* d_in, const int* in_sizes, int n_in,
                              void* d_out, int out_size, void* d_ws, size_t ws_size,
                              hipStream_t stream) {
    const float* ws_in  = (const float*)d_in[0];
    const float* bs_in  = (const float*)d_in[1];
    const float* fc1_w  = (const float*)d_in[4];
    const float* fc1_b  = (const float*)d_in[5];
    const float* ln_w   = (const float*)d_in[6];
    const float* ln_b   = (const float*)d_in[7];
    const float* gate_w = (const float*)d_in[8];
    const float* gate_b = (const float*)d_in[9];
    const float* fco_w  = (const float*)d_in[10];
    const float* fco_b  = (const float*)d_in[11];
    const float* scale  = (const float*)d_in[12];
    float* out  = (float*)d_out;
    float* feat = (float*)d_ws;

    // 192 w-stat blocks + 48 b-sort blocks (4 rows each) fill all 256 CUs in one launch
    hipLaunchKernelGGL(stats_kernel, dim3(NROW + NROW / 4), dim3(NT), 0, stream,
                       ws_in, bs_in, feat);
    hipLaunchKernelGGL(mlp_kernel, dim3(NROW), dim3(256), 0, stream,
                       feat, fc1_w, fc1_b, ln_w, ln_b, gate_w, gate_b,
                       fco_w, fco_b, scale, out);
}

// Round 2
// 413.660 us; speedup vs baseline: 2.2437x; 2.2437x over previous
//
#include <hip/hip_runtime.h>
#include <cstdint>

#define NROW 192
#define NW   262144
#define NT   1024
#define QCAP 1024
#define SEGS_CAP 8192

// ---------- monotone float<->uint transform (total order) ----------
__device__ __forceinline__ uint32_t mono(float x) {
    uint32_t u = __float_as_uint(x);
    return (u & 0x80000000u) ? ~u : (u | 0x80000000u);
}
__device__ __forceinline__ float unmono(uint32_t u) {
    uint32_t v = (u & 0x80000000u) ? (u & 0x7FFFFFFFu) : ~u;
    return __uint_as_float(v);
}
// linear-in-value bin; MUST be the same code in hist and collect sweeps
__device__ __forceinline__ int binof(float x, float lo, float s) {
    float d = (x - lo) * s;
    d = fminf(fmaxf(d, 0.0f), 4095.0f);
    return (int)d;
}

// ---------- block "find bin containing rank" ----------
__device__ void block_select(const uint32_t* hist, int nb, uint32_t rank,
                             uint32_t* sbuf, volatile uint32_t* out, int tid) {
    int per = (nb + NT - 1) / NT;
    int base = tid * per;
    uint32_t s = 0;
    for (int i = 0; i < per; ++i) { int idx = base + i; if (idx < nb) s += hist[idx]; }
    uint32_t p = s;
    int lane = tid & 63;
    #pragma unroll
    for (int off = 1; off < 64; off <<= 1) {
        uint32_t v = __shfl_up(p, off);
        if (lane >= off) p += v;
    }
    int w = tid >> 6;
    if (lane == 63) sbuf[w] = p;
    __syncthreads();
    if (tid == 0) {
        uint32_t acc = 0;
        for (int i = 0; i < 16; ++i) { uint32_t t = sbuf[i]; sbuf[16 + i] = acc; acc += t; }
    }
    __syncthreads();
    uint32_t excl = sbuf[16 + w] + p - s;
    if (rank >= excl && rank < excl + s) {
        uint32_t rem = rank - excl;
        for (int i = 0; i < per; ++i) {
            int idx = base + i;
            if (idx >= nb) break;
            uint32_t c = hist[idx];
            if (rem < c) { out[0] = (uint32_t)idx; out[1] = rem; break; }
            rem -= c;
        }
    }
    __syncthreads();
}

// ---------- exact rank-select among seg[0..cnt) keys, 3-pass LDS radix 11/11/10 ----------
__device__ uint32_t seg_select(const uint32_t* seg, uint32_t cnt, uint32_t rank,
                               uint32_t* hist2, uint32_t* sbuf,
                               volatile uint32_t* out2, int tid) {
    for (int i = tid; i < 2048; i += NT) hist2[i] = 0;
    __syncthreads();
    for (uint32_t i = tid; i < cnt; i += NT) atomicAdd(&hist2[seg[i] >> 21], 1u);
    __syncthreads();
    block_select(hist2, 2048, rank, sbuf, out2, tid);
    uint32_t b1 = out2[0], r1 = out2[1];
    __syncthreads();
    for (int i = tid; i < 2048; i += NT) hist2[i] = 0;
    __syncthreads();
    for (uint32_t i = tid; i < cnt; i += NT) {
        uint32_t k = seg[i];
        if ((k >> 21) == b1) atomicAdd(&hist2[(k >> 10) & 2047u], 1u);
    }
    __syncthreads();
    block_select(hist2, 2048, r1, sbuf, out2, tid);
    uint32_t b2 = out2[0], r2 = out2[1];
    __syncthreads();
    for (int i = tid; i < 1024; i += NT) hist2[i] = 0;
    __syncthreads();
    for (uint32_t i = tid; i < cnt; i += NT) {
        uint32_t k = seg[i];
        if ((k >> 21) == b1 && ((k >> 10) & 2047u) == b2)
            atomicAdd(&hist2[k & 1023u], 1u);
    }
    __syncthreads();
    block_select(hist2, 1024, r2, sbuf, out2, tid);
    uint32_t b3 = out2[0];
    __syncthreads();
    return (b1 << 21) + (b2 << 10) + b3;
}

// ---------- fallback: finish a rank with 2 global sweeps (12-bit mono, proven) ----------
__device__ uint32_t refine_global(const float4* p4, float med, int mode,
                                  uint32_t b1, uint32_t rem,
                                  uint32_t* hist2, uint32_t* sbuf,
                                  volatile uint32_t* out2, int tid) {
    for (int i = tid; i < 2048; i += NT) hist2[i] = 0;
    __syncthreads();
    for (int it = 0; it < 64; ++it) {
        float4 v = p4[tid + it * NT];
        float xs[4] = {v.x, v.y, v.z, v.w};
        #pragma unroll
        for (int c = 0; c < 4; ++c) {
            uint32_t u = mode ? __float_as_uint(fabsf(xs[c] - med)) : mono(xs[c]);
            if ((u >> 20) == b1) atomicAdd(&hist2[(u >> 9) & 2047u], 1u);
        }
    }
    __syncthreads();
    block_select(hist2, 2048, rem, sbuf, out2, tid);
    uint32_t b2 = out2[0], r2 = out2[1];
    __syncthreads();
    for (int i = tid; i < 512; i += NT) hist2[i] = 0;
    __syncthreads();
    for (int it = 0; it < 64; ++it) {
        float4 v = p4[tid + it * NT];
        float xs[4] = {v.x, v.y, v.z, v.w};
        #pragma unroll
        for (int c = 0; c < 4; ++c) {
            uint32_t u = mode ? __float_as_uint(fabsf(xs[c] - med)) : mono(xs[c]);
            if ((u >> 20) == b1 && ((u >> 9) & 2047u) == b2)
                atomicAdd(&hist2[u & 511u], 1u);
        }
    }
    __syncthreads();
    block_select(hist2, 512, r2, sbuf, out2, tid);
    uint32_t b3 = out2[0];
    __syncthreads();
    return (b1 << 20) + (b2 << 9) + b3;
}

// ---------- fallback path: full 12-bit 3-level select (slow, always correct) ----------
__device__ void fb_path(const float4* p4, float* feat, int row,
                        uint32_t* hist, uint32_t* hist2, uint32_t* sbuf,
                        volatile uint32_t* out2, int tid) {
    const uint32_t RANK6[6] = {65535u, 65536u, 131071u, 131072u, 196607u, 196608u};
    for (int i = tid; i < 4096; i += NT) hist[i] = 0;
    __syncthreads();
    for (int it = 0; it < 64; ++it) {
        float4 v = p4[tid + it * NT];
        float xs[4] = {v.x, v.y, v.z, v.w};
        #pragma unroll
        for (int c = 0; c < 4; ++c) atomicAdd(&hist[mono(xs[c]) >> 20], 1u);
    }
    __syncthreads();
    uint32_t bins[6], rems[6];
    for (int k = 0; k < 6; ++k) {
        block_select(hist, 4096, RANK6[k], sbuf, out2, tid);
        bins[k] = out2[0]; rems[k] = out2[1];
        __syncthreads();
    }
    float svv[6];
    for (int k = 0; k < 6; ++k)
        svv[k] = unmono(refine_global(p4, 0.f, 0, bins[k], rems[k], hist2, sbuf, out2, tid));
    if (tid == 0) {
        float* f = feat + row * 16;
        f[0] = svv[2];
        f[3] = 0.25f * svv[0] + 0.75f * svv[1];
        f[4] = 0.5f  * (svv[2] + svv[3]);
        f[5] = 0.75f * svv[4] + 0.25f * svv[5];
    }
    float med = svv[2];
    __syncthreads();
    for (int i = tid; i < 4096; i += NT) hist[i] = 0;
    __syncthreads();
    for (int it = 0; it < 64; ++it) {
        float4 v = p4[tid + it * NT];
        float xs[4] = {v.x, v.y, v.z, v.w};
        #pragma unroll
        for (int c = 0; c < 4; ++c)
            atomicAdd(&hist[__float_as_uint(fabsf(xs[c] - med)) >> 20], 1u);
    }
    __syncthreads();
    block_select(hist, 4096, 131071u, sbuf, out2, tid);
    uint32_t mb = out2[0], mr = out2[1];
    __syncthreads();
    uint32_t mu = refine_global(p4, med, 1, mb, mr, hist2, sbuf, out2, tid);
    if (tid == 0) feat[row * 16 + 1] = __uint_as_float(mu);
}

// ---------- prefix-sum helpers (hist holds exclusive prefix P after scan) ----------
__device__ __forceinline__ uint32_t Pv(const uint32_t* P, int k) {
    return (k >= 4096) ? (uint32_t)NW : P[k];
}
// upper bound on count(|x-med|<=tau) for any med in bin [mL,mR]
__device__ __forceinline__ uint32_t wup(float mL, float mR, float tau,
                                        float blo, float bsc, const uint32_t* P) {
    const int bR = binof(mR + tau, blo, bsc);
    const int bL = binof(mL - tau, blo, bsc);
    return Pv(P, bR + 1) - P[bL];
}
// lower bound on count(|x-med|<=tau) for any med in bin [mL,mR]
__device__ __forceinline__ uint32_t wlow(float mL, float mR, float tau,
                                         float blo, float bsc, const uint32_t* P) {
    const int bR = binof(mL + tau, blo, bsc);
    const int bL = binof(mR - tau, blo, bsc);
    const uint32_t a = P[bR];
    const uint32_t b = Pv(P, bL + 1);
    return (a > b) ? (a - b) : 0u;
}

// ---------- in-LDS bitonic sort of 512 floats; 256-thread group, block-wide barriers ----------
__device__ void bitonic512g(float* a, int t2) {
    for (int k = 2; k <= 512; k <<= 1) {
        for (int j = k >> 1; j > 0; j >>= 1) {
            __syncthreads();
            for (int i = t2; i < 512; i += 256) {
                int ixj = i ^ j;
                if (ixj > i) {
                    float x = a[i], y = a[ixj];
                    bool up = ((i & k) == 0);
                    if ((x > y) == up) { a[i] = y; a[ixj] = x; }
                }
            }
        }
    }
    __syncthreads();
}

// ---------- fused stats: blocks [0,NROW) = w-row robust stats (2 full sweeps),
// ----------              blocks [NROW, NROW+48) = b-row sorts (4 rows/block) ----------
__global__ __launch_bounds__(NT) void stats_kernel(const float* __restrict__ wsrc,
                                                   const float* __restrict__ bsrc,
                                                   float* __restrict__ feat) {
    const int tid = threadIdx.x;
    __shared__ uint32_t hist[4096];      // counts, then in-place exclusive prefix P, then radix scratch
    __shared__ uint32_t sbuf[1024];      // scan partials / byte table / reductions
    __shared__ uint32_t segs[SEGS_CAP];  // quantile segs (exact-packed) + MAD window
    __shared__ uint32_t ctrl[64];
    __shared__ float fctrl[8];

    // ================= b-row branch: 4 rows per block, groups of 256 =================
    if (blockIdx.x >= NROW) {
        const int g = tid >> 8, t2 = tid & 255;
        const int brow = (blockIdx.x - NROW) * 4 + g;
        float* a = ((float*)segs) + g * 512;
        float* d = ((float*)segs) + 2048 + g * 512;
        const float* p = bsrc + (size_t)brow * 512;
        for (int i = t2; i < 512; i += 256) a[i] = p[i];
        bitonic512g(a, t2);
        const float bmed = a[255];
        if (t2 == 0) {
            float* f = feat + brow * 16;
            f[7]  = bmed;
            f[9]  = a[0];
            f[10] = 0.25f * a[127] + 0.75f * a[128];
            f[11] = 0.5f  * (a[255] + a[256]);
            f[12] = 0.75f * a[383] + 0.25f * a[384];
            f[13] = a[511];
        }
        __syncthreads();
        for (int i = t2; i < 512; i += 256) d[i] = fabsf(a[i] - bmed);
        bitonic512g(d, t2);
        if (t2 == 0) feat[brow * 16 + 8] = d[255];
        return;
    }

    // ================= w-row branch =================
    const int row = blockIdx.x;
    const float4* __restrict__ p4 = (const float4*)(wsrc + (size_t)row * NW);
    const int lane = tid & 63, wv = tid >> 6;
    float* fsb = (float*)sbuf;
    volatile uint32_t* out2 = (volatile uint32_t*)(ctrl + 62);

    // ---- P0: contiguous prefix sample (32768 floats) -> linear-bin range ----
    {
        float smin = 1e30f, smax = -1e30f;
        #pragma unroll
        for (int k = 0; k < 8; ++k) {
            float4 v = p4[tid + k * NT];
            smin = fminf(smin, fminf(fminf(v.x, v.y), fminf(v.z, v.w)));
            smax = fmaxf(smax, fmaxf(fmaxf(v.x, v.y), fmaxf(v.z, v.w)));
        }
        #pragma unroll
        for (int off = 32; off > 0; off >>= 1) {
            smin = fminf(smin, __shfl_down(smin, off));
            smax = fmaxf(smax, __shfl_down(smax, off));
        }
        if (lane == 0) { fsb[wv * 2] = smin; fsb[wv * 2 + 1] = smax; }
        __syncthreads();
        if (tid == 0) {
            float mn = 1e30f, mx = -1e30f;
            for (int i = 0; i < 16; ++i) { mn = fminf(mn, fsb[i * 2]); mx = fmaxf(mx, fsb[i * 2 + 1]); }
            float span = mx - mn;
            float lo = mn - 0.0625f * span;
            float s = (span > 0.f) ? 4096.0f / (span * 1.125f) : 0.0f;
            fctrl[0] = lo; fctrl[1] = s;
        }
        __syncthreads();
    }
    const float blo = fctrl[0], bsc = fctrl[1];

    // ---- S1: full sweep — linear hist + sum + exact min/max ----
    for (int i = tid; i < 4096; i += NT) hist[i] = 0;
    __syncthreads();
    {
        float sum = 0.f, fmn = 1e30f, fmx = -1e30f;
        for (int it = 0; it < 64; it += 8) {
            float4 a8[8];
            #pragma unroll
            for (int j = 0; j < 8; ++j) a8[j] = p4[tid + (it + j) * NT];
            #pragma unroll
            for (int j = 0; j < 8; ++j) {
                float xs[4] = {a8[j].x, a8[j].y, a8[j].z, a8[j].w};
                #pragma unroll
                for (int c = 0; c < 4; ++c) {
                    float x = xs[c];
                    sum += x;
                    fmn = fminf(fmn, x);
                    fmx = fmaxf(fmx, x);
                    atomicAdd(&hist[binof(x, blo, bsc)], 1u);
                }
            }
        }
        #pragma unroll
        for (int off = 32; off > 0; off >>= 1) {
            sum += __shfl_down(sum, off);
            fmn = fminf(fmn, __shfl_down(fmn, off));
            fmx = fmaxf(fmx, __shfl_down(fmx, off));
        }
        __syncthreads();
        if (lane == 0) { fsb[wv * 4] = sum; fsb[wv * 4 + 1] = fmn; fsb[wv * 4 + 2] = fmx; }
        __syncthreads();
        if (tid == 0) { float s = 0; for (int i = 0; i < 16; ++i) s += fsb[i * 4]; feat[row * 16 + 14] = s * (1.0f / (float)NW); }
        if (tid == 1) { float m = 1e30f;  for (int i = 0; i < 16; ++i) m = fminf(m, fsb[i * 4 + 1]); feat[row * 16 + 2] = m; fctrl[2] = m; }
        if (tid == 2) { float M = -1e30f; for (int i = 0; i < 16; ++i) M = fmaxf(M, fsb[i * 4 + 2]); feat[row * 16 + 6] = M; fctrl[3] = M; }
        if (tid == 3) feat[row * 16 + 15] = 0.0f;
        __syncthreads();
    }

    // ---- SCAN: in-place hist -> exclusive prefix P; fused rank->bin find ----
    {
        const int b4 = tid * 4;
        const uint32_t v0 = hist[b4], v1 = hist[b4 + 1], v2 = hist[b4 + 2], v3 = hist[b4 + 3];
        const uint32_t s = v0 + v1 + v2 + v3;
        uint32_t p = s;
        #pragma unroll
        for (int off = 1; off < 64; off <<= 1) {
            uint32_t t = __shfl_up(p, off);
            if (lane >= off) p += t;
        }
        if (lane == 63) sbuf[wv] = p;
        __syncthreads();
        if (tid == 0) {
            uint32_t acc = 0;
            for (int i = 0; i < 16; ++i) { uint32_t t = sbuf[i]; sbuf[16 + i] = acc; acc += t; }
        }
        __syncthreads();
        const uint32_t excl = sbuf[16 + wv] + p - s;
        uint32_t ppA[5];
        ppA[0] = excl; ppA[1] = excl + v0; ppA[2] = ppA[1] + v1; ppA[3] = ppA[2] + v2; ppA[4] = ppA[3] + v3;
        hist[b4] = ppA[0]; hist[b4 + 1] = ppA[1]; hist[b4 + 2] = ppA[2]; hist[b4 + 3] = ppA[3];
        const uint32_t RANKS[6] = {65535u, 65536u, 131071u, 131072u, 196607u, 196608u};
        #pragma unroll
        for (int c = 0; c < 4; ++c) {
            #pragma unroll
            for (int q = 0; q < 6; ++q) {
                const uint32_t r = RANKS[q];
                if (ppA[c] <= r && r < ppA[c + 1]) {
                    ctrl[12 + q] = (uint32_t)(b4 + c);   // bin
                    ctrl[18 + q] = r - ppA[c];           // rem within bin
                    ctrl[48 + q] = ppA[c + 1] - ppA[c];  // bin count
                }
            }
        }
        __syncthreads();
    }

    // ---- dedup rank bins; exact-packed seg bases; init cursors/flags ----
    if (tid == 0) {
        uint32_t ndl = 0, fail = 0;
        #pragma unroll
        for (int q = 0; q < 6; ++q) {
            const uint32_t b = ctrl[12 + q];
            int jf = -1;
            for (uint32_t t = 0; t < ndl; ++t) if (ctrl[24 + t] == b) { jf = (int)t; break; }
            if (jf < 0) {
                jf = (int)ndl;
                ctrl[24 + ndl] = b;
                ctrl[30 + ndl] = ctrl[48 + q];
                ndl++;
            }
            ctrl[36 + q] = (uint32_t)jf;
        }
        uint32_t off = 0;
        for (uint32_t t = 0; t < ndl; ++t) {
            ctrl[54 + t] = off;
            if (ctrl[30 + t] > QCAP) fail = 1;
            off += ctrl[30 + t];
        }
        if (off > 6144u) fail = 1;                       // keep >=2048 MAD slots
        if (ctrl[14] == 0u || ctrl[14] == 4095u) fail = 1; // med in clamped bin: bin-center bound invalid
        ctrl[60] = off;   // MAD region base
        ctrl[10] = ndl;
        ctrl[11] = fail;
        #pragma unroll
        for (int j = 0; j < 6; ++j) ctrl[j] = 0;         // quantile cursors
        ctrl[6] = 0;  // MAD cursor
        ctrl[7] = 0;  // c_lo
        ctrl[8] = 0;  // n2theta
        ctrl[9] = 0;  // n2c
        ctrl[48] = 0xFFFFFFFFu; ctrl[49] = 0xFFFFFFFFu;  // window jlo/jhi
    }
    __syncthreads();
    if (ctrl[11]) { fb_path(p4, feat, row, hist, segs, sbuf, out2, tid); return; }

    const float wbin = 1.0f / bsc;
    const uint32_t m0 = ctrl[14];

    // ---- zero candidate-bin byte table + MAD window bounds from P (parallel) ----
    sbuf[tid] = 0;
    {
        const float mLf = blo + (float)m0 * wbin;
        const float mRf = mLf + wbin;
        #pragma unroll
        for (int c = 0; c < 4; ++c) {
            const int j = tid * 4 + c;
            const float tau = (float)j * wbin;
            const uint32_t up_j = wup(mLf, mRf, tau, blo, bsc, hist);
            if (up_j <= 131071u) {   // largest j with up<=K  (up monotone in j)
                bool bnd = (j == 4095);
                if (!bnd) bnd = (wup(mLf, mRf, (float)(j + 1) * wbin, blo, bsc, hist) > 131071u);
                if (bnd) ctrl[48] = (uint32_t)j;
            }
            const uint32_t lo_j = wlow(mLf, mRf, tau, blo, bsc, hist);
            if (lo_j >= 131072u) {   // smallest j with low>=K+1 (low monotone in j)
                bool bnd = (j == 0);
                if (!bnd) bnd = (wlow(mLf, mRf, (float)(j - 1) * wbin, blo, bsc, hist) < 131072u);
                if (bnd) ctrl[49] = (uint32_t)j;
            }
        }
    }
    __syncthreads();
    if (tid < (int)ctrl[10]) ((uint8_t*)sbuf)[ctrl[24 + tid]] = (uint8_t)(tid + 1);
    // PAD the window: Awin=(jlo-2)w guarantees t_(K) > Awin+w (check B passes);
    // Bwin=(jhi+3)w guarantees count(t<=Bwin-2w)>=K+1 (check C passes); 1 extra
    // bin each side absorbs float-edge fuzz. Tight bounds made ~45% of rows
    // fail the checks and take the 16-sweep fb_path (R1 post-mortem).
    const uint32_t jlo = ctrl[48], jhi = ctrl[49];
    float Awin = -1.0f;
    if (jlo != 0xFFFFFFFFu && jlo >= 2u) Awin = (float)(jlo - 2u) * wbin;
    float Bwin = (jhi == 0xFFFFFFFFu) ? 3.0e38f : (float)(jhi + 3u) * wbin;
    Bwin = fmaxf(Bwin, Awin + 3.0f * wbin);
    const float mtld = blo + ((float)m0 + 0.5f) * wbin;  // |med - mtld| <= w/2
    const uint32_t madbase = ctrl[60];
    __syncthreads();

    // ---- S2: single combined sweep — quantile candidates + MAD window + c_lo ----
    uint32_t myclo = 0;
    {
        const uint8_t* tbl = (const uint8_t*)sbuf;
        for (int it = 0; it < 64; it += 8) {
            float4 a8[8];
            #pragma unroll
            for (int j = 0; j < 8; ++j) a8[j] = p4[tid + (it + j) * NT];
            #pragma unroll
            for (int j = 0; j < 8; ++j) {
                float xs[4] = {a8[j].x, a8[j].y, a8[j].z, a8[j].w};
                #pragma unroll
                for (int c = 0; c < 4; ++c) {
                    float x = xs[c];
                    uint32_t m = tbl[binof(x, blo, bsc)];
                    if (m) {
                        uint32_t jj = m - 1u;
                        uint32_t pos = atomicAdd(&ctrl[jj], 1u);
                        if (pos < ctrl[30 + jj]) segs[ctrl[54 + jj] + pos] = mono(x);
                    }
                    float u = fabsf(x - mtld);
                    if (u <= Awin) myclo++;
                    else if (u <= Bwin) {
                        uint32_t pos = atomicAdd(&ctrl[6], 1u);
                        uint32_t slot = madbase + pos;
                        if (slot < SEGS_CAP) segs[slot] = __float_as_uint(x);
                    }
                }
            }
        }
    }
    __syncthreads();
    #pragma unroll
    for (int off = 32; off > 0; off >>= 1) myclo += __shfl_down(myclo, off);
    if (lane == 0) sbuf[wv] = myclo;
    __syncthreads();
    if (tid == 0) {
        uint32_t clo = 0;
        for (int i = 0; i < 16; ++i) clo += sbuf[i];
        ctrl[7] = clo;
        uint32_t fail = 0;
        const uint32_t ndl = ctrl[10];
        for (uint32_t j = 0; j < ndl; ++j) if (ctrl[j] != ctrl[30 + j]) fail = 1;
        if (ctrl[6] > SEGS_CAP - madbase) fail = 1;
        ctrl[11] = fail;
    }
    __syncthreads();
    if (ctrl[11]) { fb_path(p4, feat, row, hist, segs, sbuf, out2, tid); return; }

    // ---- all-pairs rank select: all 6 quantile ranks, one pass per dedup segment ----
    // (cnt <= QCAP=1024 enforced, typically ~200-300: one wave-group active, ~2 us)
    {
        const uint32_t ndl = ctrl[10];
        for (uint32_t j = 0; j < ndl; ++j) {
            const uint32_t cnt = ctrl[j];
            const uint32_t base = ctrl[54 + j];
            if ((uint32_t)tid < cnt) {
                const uint32_t key = segs[base + tid];
                uint32_t r = 0;
                for (uint32_t i = 0; i < cnt; ++i) {
                    const uint32_t ki = segs[base + i];
                    r += (ki < key || (ki == key && i < (uint32_t)tid)) ? 1u : 0u;
                }
                #pragma unroll
                for (int q = 0; q < 6; ++q)
                    if (ctrl[36 + q] == j && ctrl[18 + q] == r) ctrl[42 + q] = key;
            }
        }
    }
    __syncthreads();
    const float med = unmono(ctrl[44]);
    if (tid == 0) {
        float* f = feat + row * 16;
        f[0] = med;
        f[3] = 0.25f * unmono(ctrl[42]) + 0.75f * unmono(ctrl[43]);
        f[4] = 0.5f  * (med + unmono(ctrl[45]));
        f[5] = 0.75f * unmono(ctrl[46]) + 0.25f * unmono(ctrl[47]);
    }

    // ---- MAD: convert window x -> t = |x-med|, verify containment, radix select ----
    const uint32_t mcnt = ctrl[6];
    const float thq = Awin + wbin;          // theta: all c_lo-counted elements have t < theta
    const float tcq = Bwin - 2.0f * wbin;   // tau_c: all non-window elements have t > tau_c
    uint32_t n2t = 0, n2c = 0;
    for (uint32_t i = (uint32_t)tid; i < mcnt; i += NT) {
        float x = __uint_as_float(segs[madbase + i]);
        float t = fabsf(x - med);
        segs[madbase + i] = __float_as_uint(t);   // t >= 0: uint order == float order
        n2t += (t <= thq) ? 1u : 0u;
        n2c += (t <= tcq) ? 1u : 0u;
    }
    #pragma unroll
    for (int off = 32; off > 0; off >>= 1) {
        n2t += __shfl_down(n2t, off);
        n2c += __shfl_down(n2c, off);
    }
    if (lane == 0) { atomicAdd(&ctrl[8], n2t); atomicAdd(&ctrl[9], n2c); }
    __syncthreads();
    if (tid == 0) {
        const uint32_t clo = ctrl[7];
        uint32_t fail = 0;
        if (clo > 131071u) fail = 1;                    // MAD must be above counted set
        if (clo + ctrl[8] > 131071u) fail = 1;          // count(t<=theta) <= 131071 => MAD > theta
        if (clo + ctrl[9] < 131072u) fail = 1;          // count(t<=tau_c) >= 131072 => MAD <= tau_c
        if (!fail && (131071u - clo) >= mcnt) fail = 1; // target rank inside window
        ctrl[11] = fail;
    }
    __syncthreads();
    if (ctrl[11]) { fb_path(p4, feat, row, hist, segs, sbuf, out2, tid); return; }
    const uint32_t kR = 131071u - ctrl[7];
    uint32_t madu = seg_select(segs + madbase, mcnt, kR, hist, sbuf, out2, tid);
    if (tid == 0) feat[row * 16 + 1] = __uint_as_float(madu);
}

// ---------- MLP head: one block per (l,b) row; reads the completed 16-feature vector ----------
__global__ __launch_bounds__(256) void mlp_kernel(
    const float* __restrict__ feat,
    const float* __restrict__ fc1_w, const float* __restrict__ fc1_b,
    const float* __restrict__ ln_w,  const float* __restrict__ ln_b,
    const float* __restrict__ gate_w, const float* __restrict__ gate_b,
    const float* __restrict__ fco_w,  const float* __restrict__ fco_b,
    const float* __restrict__ scale,  float* __restrict__ out) {
    const int row = blockIdx.x;
    const int tid = threadIdx.x;
    const int l = row >> 6;
    __shared__ float x[16], h[64], hg[64], stats[2];

    if (tid < 16) x[tid] = feat[row * 16 + tid];
    __syncthreads();

    if (tid == 0) {
        float mu = 0.f;
        for (int i = 0; i < 16; ++i) mu += x[i];
        mu *= (1.f / 16.f);
        float var = 0.f;
        for (int i = 0; i < 16; ++i) { float dd = x[i] - mu; var += dd * dd; }
        var *= (1.f / 16.f);
        stats[0] = mu; stats[1] = rsqrtf(var + 1e-5f);
    }
    __syncthreads();
    if (tid < 16) x[tid] = (x[tid] - stats[0]) * stats[1];
    __syncthreads();
    if (tid < 64) {
        const float* wv = fc1_w + ((size_t)l * 64 + tid) * 16;
        float acc = fc1_b[l * 64 + tid];
        #pragma unroll
        for (int i = 0; i < 16; ++i) acc += x[i] * wv[i];
        h[tid] = acc;
    }
    __syncthreads();
    if (tid == 0) {
        float mu = 0.f;
        for (int i = 0; i < 64; ++i) mu += h[i];
        mu *= (1.f / 64.f);
        float var = 0.f;
        for (int i = 0; i < 64; ++i) { float dd = h[i] - mu; var += dd * dd; }
        var *= (1.f / 64.f);
        stats[0] = mu; stats[1] = rsqrtf(var + 1e-5f);
    }
    __syncthreads();
    if (tid < 64) {
        float v = (h[tid] - stats[0]) * stats[1] * ln_w[l * 64 + tid] + ln_b[l * 64 + tid];
        h[tid] = 0.5f * v * (1.0f + erff(v * 0.70710678118654752f));
    }
    __syncthreads();
    if (tid < 64) {
        const float* wv = gate_w + ((size_t)l * 64 + tid) * 64;
        float acc = gate_b[l * 64 + tid];
        #pragma unroll
        for (int i = 0; i < 64; ++i) acc += h[i] * wv[i];
        float g = 1.0f / (1.0f + expf(-acc));
        hg[tid] = h[tid] * g;
    }
    __syncthreads();
    const float sc = scale[l];
    for (int o = tid; o < 512; o += 256) {
        const float* wv = fco_w + ((size_t)l * 512 + o) * 64;
        float acc = fco_b[l * 512 + o];
        #pragma unroll
        for (int i = 0; i < 64; ++i) acc += hg[i] * wv[i];
        out[(size_t)row * 512 + o] = sinf(acc) * sc + 1.0f;
    }
}

extern "C" void kernel_launch(void* const* d_in, const int* in_sizes, int n_in,
                              void* d_out, int out_size, void* d_ws, size_t ws_size,
                              hipStream_t stream) {
    const float* ws_in  = (const float*)d_in[0];
    const float* bs_in  = (const float*)d_in[1];
    const float* fc1_w  = (const float*)d_in[4];
    const float* fc1_b  = (const float*)d_in[5];
    const float* ln_w   = (const float*)d_in[6];
    const float* ln_b   = (const float*)d_in[7];
    const float* gate_w = (const float*)d_in[8];
    const float* gate_b = (const float*)d_in[9];
    const float* fco_w  = (const float*)d_in[10];
    const float* fco_b  = (const float*)d_in[11];
    const float* scale  = (const float*)d_in[12];
    float* out  = (float*)d_out;
    float* feat = (float*)d_ws;

    // 192 w-stat blocks + 48 b-sort blocks (4 rows each) fill all 256 CUs in one launch
    hipLaunchKernelGGL(stats_kernel, dim3(NROW + NROW / 4), dim3(NT), 0, stream,
                       ws_in, bs_in, feat);
    hipLaunchKernelGGL(mlp_kernel, dim3(NROW), dim3(256), 0, stream,
                       feat, fc1_w, fc1_b, ln_w, ln_b, gate_w, gate_b,
                       fco_w, fco_b, scale, out);
}